// Round 1
// baseline (571.852 us; speedup 1.0000x reference)
//
#include <hip/hip_runtime.h>
#include <hip/hip_bf16.h>
#include <math.h>

// Problem constants
#define L 4096       // 16*16*16 spatial points
#define C 128
#define DI 256       // d_inner
#define NST 16       // d_state
#define DTR 8        // dt_rank
#define NS 3         // directions
#define NCH 64       // chunks per sequence
#define CT 64        // chunk length (NCH*CT = L)
#define R3 (NS*L)    // 12288 rows total

__device__ __forceinline__ float siluf(float x){ return x / (1.f + __expf(-x)); }
__device__ __forceinline__ float geluf(float x){ return 0.5f*x*(1.f + erff(x*0.70710678118654752f)); }

// sequence index l -> spatial linear index p, per direction
__device__ __forceinline__ int permf(int s, int l){
  if(s==0) return l;                                            // (d,h,w)
  if(s==1) return ((l&15)<<8) | ((l>>8)<<4) | ((l>>4)&15);      // l=(h,w,d)
  return (((l>>4)&15)<<8) | ((l&15)<<4) | (l>>8);               // l=(w,d,h)
}

// K0: fold out_proj (128x256) and proj (128x384) -> M[(s*256+d)*128+o]
__global__ void k_M(const float* __restrict__ opw, const float* __restrict__ pw,
                    float* __restrict__ Mw){
  int t = blockIdx.x*256 + threadIdx.x;      // 3*256*128 = 98304
  int o = t & 127, d = (t>>7) & 255, s = t>>15;
  float acc = 0.f;
  for(int c=0;c<C;c++) acc += opw[c*DI + d] * pw[o*384 + s*128 + c];
  Mw[(s*256+d)*128 + o] = acc;
}

// K1: channel-LN (eps 1e-6) then row-LN (eps 1e-5) per spatial point -> Y0[p][c]
__global__ void k_ln(const float* __restrict__ x, const float* __restrict__ lw,
                     const float* __restrict__ lb, const float* __restrict__ mw,
                     const float* __restrict__ mb, float* __restrict__ Y0){
  int p = blockIdx.x*blockDim.x + threadIdx.x;   // 0..4095
  float s=0.f, sq=0.f;
  for(int c=0;c<C;c++){ float v = x[c*L + p]; s += v; sq += v*v; }
  float mean = s*(1.f/C); float var = sq*(1.f/C) - mean*mean;
  float r1 = rsqrtf(var + 1e-6f);
  float s2=0.f, sq2=0.f;
  for(int c=0;c<C;c++){
    float v = lw[c]*((x[c*L+p]-mean)*r1) + lb[c];
    s2 += v; sq2 += v*v;
  }
  float m2 = s2*(1.f/C); float v2 = sq2*(1.f/C) - m2*m2;
  float r2 = rsqrtf(v2 + 1e-5f);
  for(int c=0;c<C;c++){
    float v = lw[c]*((x[c*L+p]-mean)*r1) + lb[c];
    Y0[p*C + c] = mw[c]*((v-m2)*r2) + mb[c];
  }
}

// K2: Z[p][j] = sum_c Y0[p][c] * W[j*128+c]   (4096x512, K=128), 64x64 tiles
__global__ void k_gemm_z(const float* __restrict__ Y0, const float* __restrict__ W,
                         float* __restrict__ Z){
  __shared__ float As[64][129];
  __shared__ float Bs[128][65];
  int p0 = blockIdx.x*64, j0 = blockIdx.y*64;
  int tid = threadIdx.x;
  // load A tile 64x128
  for(int q=0;q<8;q++){
    int f = q*1024 + tid*4; int i = f>>7; int c = f&127;
    float4 v = *(const float4*)&Y0[(p0+i)*C + c];
    As[i][c]=v.x; As[i][c+1]=v.y; As[i][c+2]=v.z; As[i][c+3]=v.w;
  }
  // load B tile (transposed): Bs[k][j] = W[(j0+j)*128+k]
  for(int q=0;q<8;q++){
    int f = q*1024 + tid*4; int j = f>>7; int k = f&127;
    float4 v = *(const float4*)&W[(j0+j)*C + k];
    Bs[k][j]=v.x; Bs[k+1][j]=v.y; Bs[k+2][j]=v.z; Bs[k+3][j]=v.w;
  }
  __syncthreads();
  int tx = tid & 15, ty = tid >> 4;
  float acc[4][4] = {};
  for(int k=0;k<128;k++){
    float a[4], b[4];
    #pragma unroll
    for(int i=0;i<4;i++) a[i] = As[ty*4+i][k];
    #pragma unroll
    for(int j=0;j<4;j++) b[j] = Bs[k][tx*4+j];
    #pragma unroll
    for(int i=0;i<4;i++)
      #pragma unroll
      for(int j=0;j<4;j++) acc[i][j] += a[i]*b[j];
  }
  #pragma unroll
  for(int i=0;i<4;i++)
    #pragma unroll
    for(int j=0;j<4;j++)
      Z[(p0+ty*4+i)*512 + j0+tx*4+j] = acc[i][j];
}

// K3: causal depthwise conv (k=4) + bias + silu along each direction's order
__global__ void k_conv(const float* __restrict__ Z, const float* __restrict__ cw,
                       const float* __restrict__ cb, float* __restrict__ xc){
  int bl = blockIdx.x;            // s*4096 + l
  int s = bl >> 12, l = bl & 4095;
  int d = threadIdx.x;            // 0..255
  float acc = cb[d];
  #pragma unroll
  for(int k=0;k<4;k++){
    int lk = l - 3 + k;
    if(lk >= 0){
      int p = permf(s, lk);
      acc += cw[d*4+k] * Z[p*512 + d];
    }
  }
  xc[bl*DI + d] = siluf(acc);
}

// K4: x_dbl = xc @ x_proj^T (40), then delta = softplus(dt @ dt_proj^T + b)
__global__ void k_xdbl(const float* __restrict__ xc, const float* __restrict__ xpw,
                       const float* __restrict__ dtw, const float* __restrict__ dtb,
                       float* __restrict__ delta, float* __restrict__ Bc,
                       float* __restrict__ Cc){
  __shared__ float xs[64][257];
  __shared__ float dt8[64][9];
  int r0 = blockIdx.x*64; int tid = threadIdx.x;
  for(int i=0;i<64;i++) xs[i][tid] = xc[(r0+i)*DI + tid];
  __syncthreads();
  for(int e=tid; e<64*40; e+=256){
    int i = e/40, col = e%40;
    float acc = 0.f;
    for(int d=0;d<DI;d++) acc += xs[i][d]*xpw[col*DI+d];
    if(col < 8)       dt8[i][col] = acc;
    else if(col < 24) Bc[(r0+i)*NST + (col-8)]  = acc;
    else              Cc[(r0+i)*NST + (col-24)] = acc;
  }
  __syncthreads();
  float w8[8];
  #pragma unroll
  for(int r=0;r<8;r++) w8[r] = dtw[tid*8+r];
  float bb = dtb[tid];
  for(int i=0;i<64;i++){
    float acc = bb;
    #pragma unroll
    for(int r=0;r<8;r++) acc += dt8[i][r]*w8[r];
    float dl = (acc > 20.f) ? acc : log1pf(__expf(acc));
    delta[(r0+i)*DI + tid] = dl;
  }
}

// K5: scan pass A — per (s,d,n,chunk) compute aggregate (P = prod a, S)
__global__ void k_scanA(const float* __restrict__ delta, const float* __restrict__ xc,
                        const float* __restrict__ Bc, const float* __restrict__ A_log,
                        float* __restrict__ aggA, float* __restrict__ aggB){
  int t = blockIdx.x*256 + threadIdx.x;
  int n = t & 15, ch = (t>>4) & 63, d = (t>>10) & 255, s = t>>18;
  float Aa = -__expf(A_log[d*NST + n]);
  float P = 1.f, S = 0.f;
  int base = s*L + ch*CT;
  for(int st=0; st<CT; st++){
    int row = base + st;
    float dl = delta[row*DI + d];
    float u  = xc[row*DI + d];
    float b  = Bc[row*NST + n];
    float a  = __expf(dl*Aa);
    S = a*S + dl*b*u;
    P *= a;
  }
  int idx = ch*R3 + (s*256+d)*16 + n;   // [chunk][sd][n] for coalesced pass B
  aggA[idx] = P; aggB[idx] = S;
}

// K6: scan pass B — prefix over 64 chunk aggregates
__global__ void k_scanB(const float* __restrict__ aggA, const float* __restrict__ aggB,
                        float* __restrict__ hIn){
  int j = blockIdx.x*256 + threadIdx.x;  // 0..12287  (= (s*256+d)*16+n)
  float h = 0.f;
  for(int c=0;c<NCH;c++){
    hIn[c*R3 + j] = h;
    h = aggA[c*R3 + j]*h + aggB[c*R3 + j];
  }
}

// K7: scan pass C — recompute with true initial state, reduce over states,
//     add u*D, gate with silu(z), store yz[s][l][d]
__global__ void k_scanC(const float* __restrict__ delta, const float* __restrict__ xc,
                        const float* __restrict__ Bc, const float* __restrict__ Cc,
                        const float* __restrict__ A_log, const float* __restrict__ Dp,
                        const float* __restrict__ Z, const float* __restrict__ hIn,
                        float* __restrict__ yz){
  int t = blockIdx.x*256 + threadIdx.x;
  int n = t & 15, ch = (t>>4) & 63, d = (t>>10) & 255, s = t>>18;
  float Aa = -__expf(A_log[d*NST + n]);
  float h  = hIn[ch*R3 + (s*256+d)*16 + n];
  float Dv = Dp[d];
  int base = s*L + ch*CT;
  float yk[4];
  #pragma unroll
  for(int q=0;q<4;q++){
    float yv = 0.f;
    for(int st2=0; st2<16; st2++){
      int row = base + q*16 + st2;
      float dl = delta[row*DI + d];
      float u  = xc[row*DI + d];
      float b  = Bc[row*NST + n];
      float cv = Cc[row*NST + n];
      float a  = __expf(dl*Aa);
      h = a*h + dl*b*u;
      float contrib = h*cv;
      contrib += __shfl_xor(contrib, 1);
      contrib += __shfl_xor(contrib, 2);
      contrib += __shfl_xor(contrib, 4);
      contrib += __shfl_xor(contrib, 8);
      if(st2 == n) yv = contrib + u*Dv;
    }
    yk[q] = yv;
  }
  #pragma unroll
  for(int q=0;q<4;q++){
    int l = ch*CT + q*16 + n;
    int p = permf(s, l);
    float zv = Z[p*512 + 256 + d];
    yz[(s*L + l)*DI + d] = yk[q] * siluf(zv);
  }
}

// K8: out_res[p][o] = x[o][p] + proj_b[o] + sum_s sum_d yz[s][p][d]*M[s*256+d][o]
__global__ void k_proj(const float* __restrict__ yz, const float* __restrict__ Mw,
                       const float* __restrict__ x, const float* __restrict__ pb,
                       float* __restrict__ out_res){
  __shared__ float As[16][65];
  __shared__ float Bs[64][132];
  int p0 = blockIdx.x*16; int tid = threadIdx.x;
  int ty = tid >> 4, tx = tid & 15;   // ty: row, tx: 8-col group
  float acc[8] = {};
  for(int kc=0; kc<12; kc++){
    int kk0 = kc*64; int s = kk0 >> 8; int d0 = kk0 & 255;
    for(int q=0;q<4;q++){
      int f = q*256 + tid; int i = f>>6; int k = f&63;
      As[i][k] = yz[(s*L + p0 + i)*DI + d0 + k];
    }
    for(int q=0;q<8;q++){
      int f = (q*256 + tid)*4; int k = f>>7; int o = f&127;
      float4 v = *(const float4*)&Mw[(kk0+k)*128 + o];
      Bs[k][o]=v.x; Bs[k][o+1]=v.y; Bs[k][o+2]=v.z; Bs[k][o+3]=v.w;
    }
    __syncthreads();
    for(int k=0;k<64;k++){
      float a = As[ty][k];
      const float4 b0 = *(const float4*)&Bs[k][tx*8];
      const float4 b1 = *(const float4*)&Bs[k][tx*8+4];
      acc[0] += a*b0.x; acc[1] += a*b0.y; acc[2] += a*b0.z; acc[3] += a*b0.w;
      acc[4] += a*b1.x; acc[5] += a*b1.y; acc[6] += a*b1.z; acc[7] += a*b1.w;
    }
    __syncthreads();
  }
  int p = p0 + ty;
  #pragma unroll
  for(int j=0;j<8;j++){
    int o = tx*8 + j;
    out_res[p*C + o] = acc[j] + x[o*L + p] + pb[o];
  }
}

// K9: LN(out_res) -> fc1+gelu -> fc2 -> +out_res, write channel-major d_out
__global__ void k_mlp(const float* __restrict__ out_res, const float* __restrict__ lw,
                      const float* __restrict__ lb, const float* __restrict__ w1,
                      const float* __restrict__ b1, const float* __restrict__ w2,
                      const float* __restrict__ b2, float* __restrict__ out){
  __shared__ float R[16][129];
  __shared__ float T[16][129];
  __shared__ float H[16][516];
  int p0 = blockIdx.x*16; int tid = threadIdx.x;
  for(int q=0;q<8;q++){
    int f = q*256 + tid; int r = f>>7; int c = f&127;
    R[r][c] = out_res[(p0+r)*C + c];
  }
  __syncthreads();
  int r = tid >> 4, sub = tid & 15;
  float s=0.f, sq=0.f;
  #pragma unroll
  for(int q=0;q<8;q++){ float v = R[r][sub*8+q]; s += v; sq += v*v; }
  s  += __shfl_xor(s,1);  s  += __shfl_xor(s,2);  s  += __shfl_xor(s,4);  s  += __shfl_xor(s,8);
  sq += __shfl_xor(sq,1); sq += __shfl_xor(sq,2); sq += __shfl_xor(sq,4); sq += __shfl_xor(sq,8);
  float mean = s*(1.f/C); float var = sq*(1.f/C) - mean*mean;
  float rr = rsqrtf(var + 1e-6f);
  #pragma unroll
  for(int q=0;q<8;q++){
    int c = sub*8+q; float v = R[r][c];
    T[r][c] = lw[c]*((v-mean)*rr) + lb[c];
  }
  __syncthreads();
  for(int e=tid; e<16*512; e+=256){
    int i = e>>9, j = e&511;
    float acc = b1[j];
    const float4* wr = (const float4*)&w1[j*C];
    for(int c4=0;c4<32;c4++){
      float4 w = wr[c4];
      acc += T[i][c4*4]*w.x + T[i][c4*4+1]*w.y + T[i][c4*4+2]*w.z + T[i][c4*4+3]*w.w;
    }
    H[i][j] = geluf(acc);
  }
  __syncthreads();
  int r2 = tid & 15, og = tid >> 4;
  for(int q=0;q<8;q++){
    int o = og*8 + q;
    float acc = b2[o];
    const float4* wr = (const float4*)&w2[o*512];
    for(int j4=0;j4<128;j4++){
      float4 w = wr[j4];
      acc += H[r2][j4*4]*w.x + H[r2][j4*4+1]*w.y + H[r2][j4*4+2]*w.z + H[r2][j4*4+3]*w.w;
    }
    out[o*L + p0 + r2] = acc + R[r2][o];
  }
}

extern "C" void kernel_launch(void* const* d_in, const int* in_sizes, int n_in,
                              void* d_out, int out_size, void* d_ws, size_t ws_size,
                              hipStream_t stream) {
  const float* x     = (const float*)d_in[0];
  const float* ln_w  = (const float*)d_in[1];
  const float* ln_b  = (const float*)d_in[2];
  const float* mw    = (const float*)d_in[3];
  const float* mb    = (const float*)d_in[4];
  const float* ipw   = (const float*)d_in[5];
  const float* cw    = (const float*)d_in[6];
  const float* cb    = (const float*)d_in[7];
  const float* xpw   = (const float*)d_in[8];
  const float* dtw   = (const float*)d_in[9];
  const float* dtb   = (const float*)d_in[10];
  const float* A_log = (const float*)d_in[11];
  const float* Dp    = (const float*)d_in[12];
  const float* opw   = (const float*)d_in[13];
  const float* pw    = (const float*)d_in[14];
  const float* pb    = (const float*)d_in[15];
  const float* w1    = (const float*)d_in[16];
  const float* b1    = (const float*)d_in[17];
  const float* w2    = (const float*)d_in[18];
  const float* b2    = (const float*)d_in[19];
  float* out = (float*)d_out;

  float* ws = (float*)d_ws;
  float* Y0    = ws;                      // 4096*128      = 524288
  float* Z     = Y0    + 524288;          // 4096*512      = 2097152
  float* xc    = Z     + 2097152;         // 12288*256     = 3145728
  float* delta = xc    + 3145728;         // 12288*256     = 3145728
  float* Bc    = delta + 3145728;         // 12288*16      = 196608
  float* Cc    = Bc    + 196608;          // 12288*16      = 196608
  float* aggA  = Cc    + 196608;          // 64*12288      = 786432
  float* aggB  = aggA  + 786432;          // 786432
  float* hIn   = aggB  + 786432;          // 786432
  float* yz    = hIn   + 786432;          // 12288*256     = 3145728
  float* Mw    = yz    + 3145728;         // 3*256*128     = 98304
  float* ores  = Mw    + 98304;           // 4096*128      = 524288

  k_M    <<<384, 256, 0, stream>>>(opw, pw, Mw);
  k_ln   <<<16, 256, 0, stream>>>(x, ln_w, ln_b, mw, mb, Y0);
  k_gemm_z<<<dim3(64,8), 256, 0, stream>>>(Y0, ipw, Z);
  k_conv <<<R3, 256, 0, stream>>>(Z, cw, cb, xc);
  k_xdbl <<<R3/64, 256, 0, stream>>>(xc, xpw, dtw, dtb, delta, Bc, Cc);
  k_scanA<<<3072, 256, 0, stream>>>(delta, xc, Bc, A_log, aggA, aggB);
  k_scanB<<<48, 256, 0, stream>>>(aggA, aggB, hIn);
  k_scanC<<<3072, 256, 0, stream>>>(delta, xc, Bc, Cc, A_log, Dp, Z, hIn, yz);
  k_proj <<<256, 256, 0, stream>>>(yz, Mw, x, pb, ores);
  k_mlp  <<<256, 256, 0, stream>>>(ores, ln_w, ln_b, w1, b1, w2, b2, out);
}

// Round 2
// 364.586 us; speedup vs baseline: 1.5685x; 1.5685x over previous
//
#include <hip/hip_runtime.h>
#include <hip/hip_bf16.h>
#include <math.h>

#define L 4096
#define C 128
#define DI 256
#define NST 16
#define NS 3
#define NCH 128
#define CT 32
#define R3 12288   // (s,d,n) state count = 3*256*16

__device__ __forceinline__ float siluf(float x){ return x / (1.f + __expf(-x)); }
__device__ __forceinline__ float geluf(float x){ return 0.5f*x*(1.f + erff(x*0.70710678118654752f)); }

__device__ __forceinline__ int permf(int s, int l){
  if(s==0) return l;
  if(s==1) return ((l&15)<<8) | ((l>>8)<<4) | ((l>>4)&15);
  return (((l>>4)&15)<<8) | ((l&15)<<4) | (l>>8);
}

// K0: fold out_proj & proj -> M[(s*256+d)*128+o]; pw reads are block-uniform (s_loads)
__global__ void k_M(const float* __restrict__ opw, const float* __restrict__ pw,
                    float* __restrict__ Mw){
  int b = blockIdx.x;              // s*128+o
  int o = b & 127, s = b >> 7;
  int d = threadIdx.x;
  float acc = 0.f;
  for(int c=0;c<C;c++) acc += opw[c*DI + d] * pw[o*384 + s*128 + c];
  Mw[(s*256+d)*128 + o] = acc;
}

// K1: channel-LN (1e-6) then row-LN (1e-5) per point -> Y0[p][c]
__global__ void k_ln(const float* __restrict__ x, const float* __restrict__ lw,
                     const float* __restrict__ lb, const float* __restrict__ mw,
                     const float* __restrict__ mb, float* __restrict__ Y0){
  int p = blockIdx.x*64 + threadIdx.x;
  float s=0.f, sq=0.f;
  #pragma unroll 16
  for(int c=0;c<C;c++){ float v = x[c*L + p]; s += v; sq += v*v; }
  float mean = s*(1.f/C); float var = sq*(1.f/C) - mean*mean;
  float r1 = rsqrtf(var + 1e-6f);
  float s2=0.f, sq2=0.f;
  #pragma unroll 16
  for(int c=0;c<C;c++){
    float v = lw[c]*((x[c*L+p]-mean)*r1) + lb[c];
    s2 += v; sq2 += v*v;
  }
  float m2 = s2*(1.f/C); float v2 = sq2*(1.f/C) - m2*m2;
  float r2 = rsqrtf(v2 + 1e-5f);
  #pragma unroll 16
  for(int c=0;c<C;c++){
    float v = lw[c]*((x[c*L+p]-mean)*r1) + lb[c];
    Y0[p*C + c] = mw[c]*((v-m2)*r2) + mb[c];
  }
}

// K2: Z[p][j] = sum_c Y0[p][c]*ipw[j][c]  (4096x512, K=128)  64x64 tiles
__global__ void k_gemm_z(const float* __restrict__ A, const float* __restrict__ Bw,
                         float* __restrict__ Z){
  __shared__ float As[64][129];
  __shared__ float Bs[64][129];
  int p0 = blockIdx.x*64, j0 = blockIdx.y*64;
  int tid = threadIdx.x;
  for(int q=0;q<8;q++){
    int f = q*1024 + tid*4; int r = f>>7, k = f&127;
    float4 a = *(const float4*)&A[(p0+r)*C + k];
    As[r][k]=a.x; As[r][k+1]=a.y; As[r][k+2]=a.z; As[r][k+3]=a.w;
    float4 b = *(const float4*)&Bw[(j0+r)*C + k];
    Bs[r][k]=b.x; Bs[r][k+1]=b.y; Bs[r][k+2]=b.z; Bs[r][k+3]=b.w;
  }
  __syncthreads();
  int og = tid & 15, r4 = tid >> 4;
  float acc[4][4] = {};
  for(int k=0;k<128;k++){
    float a[4], b[4];
    #pragma unroll
    for(int i=0;i<4;i++) a[i] = As[r4*4+i][k];
    #pragma unroll
    for(int j=0;j<4;j++) b[j] = Bs[og+16*j][k];
    #pragma unroll
    for(int i=0;i<4;i++)
      #pragma unroll
      for(int j=0;j<4;j++) acc[i][j] += a[i]*b[j];
  }
  #pragma unroll
  for(int i=0;i<4;i++)
    #pragma unroll
    for(int j=0;j<4;j++)
      Z[(p0+r4*4+i)*512 + j0 + og + 16*j] = acc[i][j];
}

// K3: causal depthwise conv (k=4) + bias + silu
__global__ void k_conv(const float* __restrict__ Z, const float* __restrict__ cw,
                       const float* __restrict__ cb, float* __restrict__ xc){
  int bl = blockIdx.x;            // s*4096 + l
  int s = bl >> 12, l = bl & 4095;
  int d = threadIdx.x;
  float acc = cb[d];
  #pragma unroll
  for(int k=0;k<4;k++){
    int lk = l - 3 + k;
    if(lk >= 0){
      int p = permf(s, lk);
      acc += cw[d*4+k] * Z[p*512 + d];
    }
  }
  xc[bl*DI + d] = siluf(acc);
}

// K4: x_dbl = xc @ x_proj^T ; delta = softplus(dt @ dt_proj^T + b)
__global__ void k_xdbl(const float* __restrict__ xc, const float* __restrict__ xpw,
                       const float* __restrict__ dtw, const float* __restrict__ dtb,
                       float* __restrict__ delta, float* __restrict__ Bc,
                       float* __restrict__ Cc){
  __shared__ float xs[64][257];
  __shared__ float dt8[64][9];
  int r0 = blockIdx.x*64; int tid = threadIdx.x;
  for(int i=0;i<64;i++) xs[i][tid] = xc[(r0+i)*DI + tid];
  __syncthreads();
  for(int e=tid; e<64*40; e+=256){
    int i = e/40, col = e%40;
    float acc = 0.f;
    for(int d=0;d<DI;d++) acc += xs[i][d]*xpw[col*DI+d];
    if(col < 8)       dt8[i][col] = acc;
    else if(col < 24) Bc[(r0+i)*NST + (col-8)]  = acc;
    else              Cc[(r0+i)*NST + (col-24)] = acc;
  }
  __syncthreads();
  float w8[8];
  #pragma unroll
  for(int r=0;r<8;r++) w8[r] = dtw[tid*8+r];
  float bb = dtb[tid];
  for(int i=0;i<64;i++){
    float acc = bb;
    #pragma unroll
    for(int r=0;r<8;r++) acc += dt8[i][r]*w8[r];
    float dl = (acc > 20.f) ? acc : log1pf(__expf(acc));
    delta[(r0+i)*DI + tid] = dl;
  }
}

// K5: scan pass A — lanes=d coalesced; 4 states/thread; chunk aggregates (P,S)
__global__ void k_scanA(const float* __restrict__ delta, const float* __restrict__ xc,
                        const float* __restrict__ Bc, const float* __restrict__ A_log,
                        float* __restrict__ aggA, float* __restrict__ aggB){
  int b = blockIdx.x;                       // 1536 = 3*128*4
  int ng = b & 3, ch = (b>>2)&127, s = b>>9;
  int d = threadIdx.x;
  int n0 = ng*4;
  float Aa[4], P[4] = {1.f,1.f,1.f,1.f}, S[4] = {0.f,0.f,0.f,0.f};
  #pragma unroll
  for(int j=0;j<4;j++) Aa[j] = -__expf(A_log[d*NST + n0 + j]);
  int base = s*L + ch*CT;
  for(int st=0; st<CT; st++){
    int row = base + st;
    float dl = delta[row*DI + d];
    float u  = xc[row*DI + d];
    float4 bv = *(const float4*)&Bc[row*NST + n0];
    float dlu = dl*u;
    float a;
    a = __expf(dl*Aa[0]); S[0] = a*S[0] + dlu*bv.x; P[0] *= a;
    a = __expf(dl*Aa[1]); S[1] = a*S[1] + dlu*bv.y; P[1] *= a;
    a = __expf(dl*Aa[2]); S[2] = a*S[2] + dlu*bv.z; P[2] *= a;
    a = __expf(dl*Aa[3]); S[3] = a*S[3] + dlu*bv.w; P[3] *= a;
  }
  int idx0 = ch*R3 + s*256 + d;
  #pragma unroll
  for(int j=0;j<4;j++){
    int idx = idx0 + (n0+j)*768;
    aggA[idx] = P[j]; aggB[idx] = S[j];
  }
}

// K6: prefix over 128 chunk aggregates
__global__ void k_scanB(const float* __restrict__ aggA, const float* __restrict__ aggB,
                        float* __restrict__ hIn){
  int j = blockIdx.x*256 + threadIdx.x;  // < 12288
  float h = 0.f;
  for(int c=0;c<NCH;c++){
    hIn[c*R3 + j] = h;
    h = aggA[c*R3 + j]*h + aggB[c*R3 + j];
  }
}

// K7: scan pass C — lanes=d, all 16 states per thread, gate + store yz
__global__ void k_scanC(const float* __restrict__ delta, const float* __restrict__ xc,
                        const float* __restrict__ Bc, const float* __restrict__ Cc,
                        const float* __restrict__ A_log, const float* __restrict__ Dp,
                        const float* __restrict__ Z, const float* __restrict__ hIn,
                        float* __restrict__ yz){
  int b = blockIdx.x;                 // 384 = 3*128
  int ch = b & 127, s = b >> 7;
  int d = threadIdx.x;
  float Aa[16], h[16];
  #pragma unroll
  for(int n=0;n<16;n++) Aa[n] = -__expf(A_log[d*NST + n]);
  #pragma unroll
  for(int n=0;n<16;n++) h[n] = hIn[ch*R3 + n*768 + s*256 + d];
  float Dv = Dp[d];
  int base = s*L + ch*CT;
  for(int st=0; st<CT; st++){
    int row = base + st;
    float dl = delta[row*DI + d];
    float u  = xc[row*DI + d];
    float dlu = dl*u;
    const float4* Bp = (const float4*)&Bc[row*NST];
    const float4* Cp = (const float4*)&Cc[row*NST];
    float y = u*Dv;
    #pragma unroll
    for(int q=0;q<4;q++){
      float4 bv = Bp[q], cv = Cp[q];
      float a;
      a = __expf(dl*Aa[4*q+0]); h[4*q+0] = a*h[4*q+0] + dlu*bv.x; y += h[4*q+0]*cv.x;
      a = __expf(dl*Aa[4*q+1]); h[4*q+1] = a*h[4*q+1] + dlu*bv.y; y += h[4*q+1]*cv.y;
      a = __expf(dl*Aa[4*q+2]); h[4*q+2] = a*h[4*q+2] + dlu*bv.z; y += h[4*q+2]*cv.z;
      a = __expf(dl*Aa[4*q+3]); h[4*q+3] = a*h[4*q+3] + dlu*bv.w; y += h[4*q+3]*cv.w;
    }
    int l = ch*CT + st;
    int p = permf(s, l);
    float zv = Z[p*512 + 256 + d];
    yz[(s*L + l)*DI + d] = y * siluf(zv);
  }
}

// K8: out1 partials: pp[kc] = yz_slice @ M_slice  (tile 64x128, split-K=6)
__global__ void k_proj(const float* __restrict__ yz, const float* __restrict__ Mw,
                       float* __restrict__ pp){
  __shared__ float As[64][129];
  __shared__ float Bs[128][129];
  int p0 = blockIdx.x*64; int kc = blockIdx.y;  // 0..5
  int s = kc >> 1, d0 = (kc & 1)*128;
  int tid = threadIdx.x;
  for(int q=0;q<8;q++){
    int f = q*1024 + tid*4; int r = f>>7, k = f&127;
    float4 a = *(const float4*)&yz[(s*L + p0 + r)*DI + d0 + k];
    As[r][k]=a.x; As[r][k+1]=a.y; As[r][k+2]=a.z; As[r][k+3]=a.w;
  }
  for(int q=0;q<16;q++){
    int f = q*1024 + tid*4; int k = f>>7, o = f&127;  // f4 along o
    float4 b = *(const float4*)&Mw[(s*256 + d0 + k)*128 + o];
    Bs[o][k]=b.x; Bs[o+1][k]=b.y; Bs[o+2][k]=b.z; Bs[o+3][k]=b.w;
  }
  __syncthreads();
  int og = tid & 15, r4 = tid >> 4;
  float acc[4][8] = {};
  for(int k=0;k<128;k++){
    float a[4];
    #pragma unroll
    for(int i=0;i<4;i++) a[i] = As[r4*4+i][k];
    #pragma unroll
    for(int j=0;j<8;j++){
      float bb = Bs[og+16*j][k];
      #pragma unroll
      for(int i=0;i<4;i++) acc[i][j] += a[i]*bb;
    }
  }
  float* dst = pp + kc*524288;
  #pragma unroll
  for(int i=0;i<4;i++)
    #pragma unroll
    for(int j=0;j<8;j++)
      dst[(p0+r4*4+i)*C + og + 16*j] = acc[i][j];
}

// K8b: ores = sum(pp) + x^T + pb
__global__ void k_pred(const float* __restrict__ pp, const float* __restrict__ x,
                       const float* __restrict__ pb, float* __restrict__ ores){
  __shared__ float Xs[16][129];
  int p0 = blockIdx.x*16; int tid = threadIdx.x;
  for(int q=0;q<8;q++){
    int f = q*256 + tid; int pl = f&15, o = f>>4;
    Xs[pl][o] = x[o*L + p0 + pl];
  }
  __syncthreads();
  for(int q=0;q<8;q++){
    int f = q*256 + tid; int o = f&127, pl = f>>7;
    int idx = (p0+pl)*C + o;
    float v = pp[idx] + pp[524288+idx] + pp[1048576+idx]
            + pp[1572864+idx] + pp[2097152+idx] + pp[2621440+idx];
    ores[idx] = v + Xs[pl][o] + pb[o];
  }
}

// K9a: T = LN(ores)  (eps 1e-6, ln_w/ln_b)
__global__ void k_ln2(const float* __restrict__ ores, const float* __restrict__ lw,
                      const float* __restrict__ lb, float* __restrict__ T){
  __shared__ float R[16][129];
  __shared__ float Ts[16][129];
  int p0 = blockIdx.x*16; int tid = threadIdx.x;
  for(int q=0;q<8;q++){
    int f = q*256 + tid; int r = f>>7, c = f&127;
    R[r][c] = ores[(p0+r)*C + c];
  }
  __syncthreads();
  int r = tid >> 4, sub = tid & 15;
  float s=0.f, sq=0.f;
  #pragma unroll
  for(int q=0;q<8;q++){ float v = R[r][sub*8+q]; s += v; sq += v*v; }
  s  += __shfl_xor(s,1);  s  += __shfl_xor(s,2);  s  += __shfl_xor(s,4);  s  += __shfl_xor(s,8);
  sq += __shfl_xor(sq,1); sq += __shfl_xor(sq,2); sq += __shfl_xor(sq,4); sq += __shfl_xor(sq,8);
  float mean = s*(1.f/C); float var = sq*(1.f/C) - mean*mean;
  float rr = rsqrtf(var + 1e-6f);
  #pragma unroll
  for(int q=0;q<8;q++){
    int c = sub*8+q; float v = R[r][c];
    Ts[r][c] = lw[c]*((v-mean)*rr) + lb[c];
  }
  __syncthreads();
  for(int q=0;q<8;q++){
    int f = q*256 + tid; int r2 = f>>7, c = f&127;
    T[(p0+r2)*C + c] = Ts[r2][c];
  }
}

// K9b: H = gelu(T @ w1^T + b1)  (4096x512, K=128)
__global__ void k_fc1(const float* __restrict__ T, const float* __restrict__ w1,
                      const float* __restrict__ b1, float* __restrict__ H){
  __shared__ float As[64][129];
  __shared__ float Bs[64][129];
  int p0 = blockIdx.x*64, j0 = blockIdx.y*64;
  int tid = threadIdx.x;
  for(int q=0;q<8;q++){
    int f = q*1024 + tid*4; int r = f>>7, k = f&127;
    float4 a = *(const float4*)&T[(p0+r)*C + k];
    As[r][k]=a.x; As[r][k+1]=a.y; As[r][k+2]=a.z; As[r][k+3]=a.w;
    float4 b = *(const float4*)&w1[(j0+r)*C + k];
    Bs[r][k]=b.x; Bs[r][k+1]=b.y; Bs[r][k+2]=b.z; Bs[r][k+3]=b.w;
  }
  __syncthreads();
  int og = tid & 15, r4 = tid >> 4;
  float acc[4][4] = {};
  for(int k=0;k<128;k++){
    float a[4], b[4];
    #pragma unroll
    for(int i=0;i<4;i++) a[i] = As[r4*4+i][k];
    #pragma unroll
    for(int j=0;j<4;j++) b[j] = Bs[og+16*j][k];
    #pragma unroll
    for(int i=0;i<4;i++)
      #pragma unroll
      for(int j=0;j<4;j++) acc[i][j] += a[i]*b[j];
  }
  #pragma unroll
  for(int i=0;i<4;i++)
    #pragma unroll
    for(int j=0;j<4;j++){
      int jj = j0 + og + 16*j;
      H[(p0+r4*4+i)*512 + jj] = geluf(acc[i][j] + b1[jj]);
    }
}

// K9c: fc2 partials (tile 64x128, split-K=4)
__global__ void k_fc2(const float* __restrict__ H, const float* __restrict__ w2,
                      float* __restrict__ fp){
  __shared__ float As[64][129];
  __shared__ float Bs[128][129];
  int p0 = blockIdx.x*64; int kc = blockIdx.y; int k0 = kc*128;
  int tid = threadIdx.x;
  for(int q=0;q<8;q++){
    int f = q*1024 + tid*4; int r = f>>7, k = f&127;
    float4 a = *(const float4*)&H[(p0+r)*512 + k0 + k];
    As[r][k]=a.x; As[r][k+1]=a.y; As[r][k+2]=a.z; As[r][k+3]=a.w;
  }
  for(int q=0;q<16;q++){
    int f = q*1024 + tid*4; int o = f>>7, k = f&127;
    float4 b = *(const float4*)&w2[o*512 + k0 + k];
    Bs[o][k]=b.x; Bs[o][k+1]=b.y; Bs[o][k+2]=b.z; Bs[o][k+3]=b.w;
  }
  __syncthreads();
  int og = tid & 15, r4 = tid >> 4;
  float acc[4][8] = {};
  for(int k=0;k<128;k++){
    float a[4];
    #pragma unroll
    for(int i=0;i<4;i++) a[i] = As[r4*4+i][k];
    #pragma unroll
    for(int j=0;j<8;j++){
      float bb = Bs[og+16*j][k];
      #pragma unroll
      for(int i=0;i<4;i++) acc[i][j] += a[i]*bb;
    }
  }
  float* dst = fp + kc*524288;
  #pragma unroll
  for(int i=0;i<4;i++)
    #pragma unroll
    for(int j=0;j<8;j++)
      dst[(p0+r4*4+i)*C + og + 16*j] = acc[i][j];
}

// K9d: out = sum(fp) + b2 + ores, transposed (channel-major) store via LDS
__global__ void k_fred(const float* __restrict__ fp, const float* __restrict__ b2,
                       const float* __restrict__ ores, float* __restrict__ out){
  __shared__ float S[128][17];
  int p0 = blockIdx.x*16; int tid = threadIdx.x;
  for(int q=0;q<8;q++){
    int f = q*256 + tid; int o = f&127, pl = f>>7;
    int idx = (p0+pl)*C + o;
    float v = fp[idx] + fp[524288+idx] + fp[1048576+idx] + fp[1572864+idx];
    S[o][pl] = v + b2[o] + ores[idx];
  }
  __syncthreads();
  for(int q=0;q<8;q++){
    int f = q*256 + tid; int pl = f&15, o = f>>4;
    out[o*L + p0 + pl] = S[o][pl];
  }
}

extern "C" void kernel_launch(void* const* d_in, const int* in_sizes, int n_in,
                              void* d_out, int out_size, void* d_ws, size_t ws_size,
                              hipStream_t stream) {
  const float* x     = (const float*)d_in[0];
  const float* ln_w  = (const float*)d_in[1];
  const float* ln_b  = (const float*)d_in[2];
  const float* mw    = (const float*)d_in[3];
  const float* mb    = (const float*)d_in[4];
  const float* ipw   = (const float*)d_in[5];
  const float* cw    = (const float*)d_in[6];
  const float* cb    = (const float*)d_in[7];
  const float* xpw   = (const float*)d_in[8];
  const float* dtw   = (const float*)d_in[9];
  const float* dtb   = (const float*)d_in[10];
  const float* A_log = (const float*)d_in[11];
  const float* Dp    = (const float*)d_in[12];
  const float* opw   = (const float*)d_in[13];
  const float* pw    = (const float*)d_in[14];
  const float* pb    = (const float*)d_in[15];
  const float* w1    = (const float*)d_in[16];
  const float* b1    = (const float*)d_in[17];
  const float* w2    = (const float*)d_in[18];
  const float* b2    = (const float*)d_in[19];
  float* out = (float*)d_out;

  float* ws = (float*)d_ws;
  float* Y0    = ws;                       // 524288
  float* Z     = Y0    + 524288;           // 2097152
  float* xc    = Z     + 2097152;          // 3145728
  float* delta = xc    + 3145728;          // 3145728
  float* Bc    = delta + 3145728;          // 196608
  float* Cc    = Bc    + 196608;           // 196608
  float* aggA  = Cc    + 196608;           // 1572864
  float* aggB  = aggA  + 1572864;          // 1572864
  float* hIn   = aggB  + 1572864;          // 1572864
  float* Mw    = hIn   + 1572864;          // 98304
  float* ores  = Mw    + 98304;            // 524288
  // aliases (dead-after-scanC regions reused)
  float* yz = aggA;    // 3145728 (aggA+aggB), written by scanC after scanB consumed them
  float* pp = delta;   // 6*524288, written by k_proj after scanC
  float* T  = hIn;     // 524288, written after hIn's last read (scanC)
  float* H  = Z;       // 2097152, written after Z's last read (scanC)
  float* fp = xc;      // 4*524288, written after xc's last read (scanC)

  k_M    <<<384, 256, 0, stream>>>(opw, pw, Mw);
  k_ln   <<<64, 64, 0, stream>>>(x, ln_w, ln_b, mw, mb, Y0);
  k_gemm_z<<<dim3(64,8), 256, 0, stream>>>(Y0, ipw, Z);
  k_conv <<<NS*L, 256, 0, stream>>>(Z, cw, cb, xc);
  k_xdbl <<<NS*L/64, 256, 0, stream>>>(xc, xpw, dtw, dtb, delta, Bc, Cc);
  k_scanA<<<1536, 256, 0, stream>>>(delta, xc, Bc, A_log, aggA, aggB);
  k_scanB<<<48, 256, 0, stream>>>(aggA, aggB, hIn);
  k_scanC<<<384, 256, 0, stream>>>(delta, xc, Bc, Cc, A_log, Dp, Z, hIn, yz);
  k_proj <<<dim3(64,6), 256, 0, stream>>>(yz, Mw, pp);
  k_pred <<<256, 256, 0, stream>>>(pp, x, pb, ores);
  k_ln2  <<<256, 256, 0, stream>>>(ores, ln_w, ln_b, T);
  k_fc1  <<<dim3(64,8), 256, 0, stream>>>(T, w1, b1, H);
  k_fc2  <<<dim3(64,4), 256, 0, stream>>>(H, w2, fp);
  k_fred <<<256, 256, 0, stream>>>(fp, b2, ores, out);
}

// Round 3
// 307.592 us; speedup vs baseline: 1.8591x; 1.1853x over previous
//
#include <hip/hip_runtime.h>
#include <hip/hip_bf16.h>
#include <math.h>

#define L 4096
#define C 128
#define DI 256
#define NST 16
#define NS 3
#define NCH 128
#define CT 32
#define R3 12288   // (s,d,n) state count = 3*256*16

__device__ __forceinline__ float siluf(float x){ return x / (1.f + __expf(-x)); }
__device__ __forceinline__ float geluf(float x){ return 0.5f*x*(1.f + erff(x*0.70710678118654752f)); }

__device__ __forceinline__ int permf(int s, int l){
  if(s==0) return l;
  if(s==1) return ((l&15)<<8) | ((l>>8)<<4) | ((l>>4)&15);
  return (((l>>4)&15)<<8) | ((l&15)<<4) | (l>>8);
}

// K0: fold out_proj & proj -> M[(s*256+d)*128+o]
__global__ void k_M(const float* __restrict__ opw, const float* __restrict__ pw,
                    float* __restrict__ Mw){
  int b = blockIdx.x;              // s*128+o
  int o = b & 127, s = b >> 7;
  int d = threadIdx.x;
  float acc = 0.f;
  for(int c=0;c<C;c++) acc += opw[c*DI + d] * pw[o*384 + s*128 + c];
  Mw[(s*256+d)*128 + o] = acc;
}

// K2: fused LN(channel,1e-6)+LN(row,1e-5) on x-tile, then Z = Y0 @ ipw^T
__global__ void k_lngemm(const float* __restrict__ x, const float* __restrict__ lw,
                         const float* __restrict__ lb, const float* __restrict__ mw,
                         const float* __restrict__ mb, const float* __restrict__ ipw,
                         float* __restrict__ Z){
  __shared__ float As[64][129];
  __shared__ float Bs[64][129];
  int p0 = blockIdx.x*64, j0 = blockIdx.y*64;
  int tid = threadIdx.x;
  // stage x tile transposed: As[p][c] = x[c*L + p0+p]
  for(int q=0;q<8;q++){
    int idx = q*256 + tid;          // 0..2047
    int cc = idx >> 4;              // 0..127
    int pg = idx & 15;              // p = pg*4
    float4 v = *(const float4*)&x[cc*L + p0 + pg*4];
    As[pg*4+0][cc]=v.x; As[pg*4+1][cc]=v.y; As[pg*4+2][cc]=v.z; As[pg*4+3][cc]=v.w;
  }
  for(int q=0;q<8;q++){
    int f = q*1024 + tid*4; int r = f>>7, k = f&127;
    float4 b = *(const float4*)&ipw[(j0+r)*C + k];
    Bs[r][k]=b.x; Bs[r][k+1]=b.y; Bs[r][k+2]=b.z; Bs[r][k+3]=b.w;
  }
  __syncthreads();
  // LN in LDS: thread (r=tid>>2, kg=tid&3), 32 channels per thread
  {
    int r = tid>>2, kg = tid&3;
    float s=0.f, sq=0.f;
    #pragma unroll
    for(int i=0;i<32;i++){
      int k = kg*32 + ((i + kg*8)&31);
      float v = As[r][k]; s += v; sq += v*v;
    }
    s  += __shfl_xor(s,1);  s  += __shfl_xor(s,2);
    sq += __shfl_xor(sq,1); sq += __shfl_xor(sq,2);
    float m1 = s*(1.f/C);
    float r1 = rsqrtf(sq*(1.f/C) - m1*m1 + 1e-6f);
    float s2=0.f, sq2=0.f;
    #pragma unroll
    for(int i=0;i<32;i++){
      int k = kg*32 + ((i + kg*8)&31);
      float t = lw[k]*((As[r][k]-m1)*r1) + lb[k];
      s2 += t; sq2 += t*t;
    }
    s2  += __shfl_xor(s2,1);  s2  += __shfl_xor(s2,2);
    sq2 += __shfl_xor(sq2,1); sq2 += __shfl_xor(sq2,2);
    float m2 = s2*(1.f/C);
    float r2 = rsqrtf(sq2*(1.f/C) - m2*m2 + 1e-5f);
    #pragma unroll
    for(int i=0;i<32;i++){
      int k = kg*32 + ((i + kg*8)&31);
      float t = lw[k]*((As[r][k]-m1)*r1) + lb[k];
      As[r][k] = mw[k]*((t-m2)*r2) + mb[k];
    }
  }
  __syncthreads();
  int og = tid & 15, r4 = tid >> 4;
  float acc[4][4] = {};
  for(int k=0;k<128;k++){
    float a[4], b[4];
    #pragma unroll
    for(int i=0;i<4;i++) a[i] = As[r4*4+i][k];
    #pragma unroll
    for(int j=0;j<4;j++) b[j] = Bs[og+16*j][k];
    #pragma unroll
    for(int i=0;i<4;i++)
      #pragma unroll
      for(int j=0;j<4;j++) acc[i][j] += a[i]*b[j];
  }
  #pragma unroll
  for(int i=0;i<4;i++)
    #pragma unroll
    for(int j=0;j<4;j++)
      Z[(p0+r4*4+i)*512 + j0 + og + 16*j] = acc[i][j];
}

// K3: causal depthwise conv (k=4) + bias + silu
__global__ void k_conv(const float* __restrict__ Z, const float* __restrict__ cw,
                       const float* __restrict__ cb, float* __restrict__ xc){
  int bl = blockIdx.x;            // s*4096 + l
  int s = bl >> 12, l = bl & 4095;
  int d = threadIdx.x;
  float acc = cb[d];
  #pragma unroll
  for(int k=0;k<4;k++){
    int lk = l - 3 + k;
    if(lk >= 0){
      int p = permf(s, lk);
      acc += cw[d*4+k] * Z[p*512 + d];
    }
  }
  xc[bl*DI + d] = siluf(acc);
}

// K4a: x_dbl = xc @ x_proj^T — one wave per row, shuffle-reduced
__global__ void k_xdbl1(const float* __restrict__ xc, const float* __restrict__ xpw,
                        float* __restrict__ dt, float* __restrict__ Bc,
                        float* __restrict__ Cc){
  int row = blockIdx.x*4 + (threadIdx.x>>6);
  int lane = threadIdx.x & 63;
  float4 xv = *(const float4*)&xc[row*DI + lane*4];
  float res = 0.f;
  #pragma unroll
  for(int col=0; col<40; col++){
    float4 wv = *(const float4*)&xpw[col*DI + lane*4];
    float p = xv.x*wv.x + xv.y*wv.y + xv.z*wv.z + xv.w*wv.w;
    p += __shfl_xor(p,1); p += __shfl_xor(p,2); p += __shfl_xor(p,4);
    p += __shfl_xor(p,8); p += __shfl_xor(p,16); p += __shfl_xor(p,32);
    if(lane == col) res = p;
  }
  if(lane < 8)       dt[row*8 + lane] = res;
  else if(lane < 24) Bc[row*16 + lane - 8]  = res;
  else if(lane < 40) Cc[row*16 + lane - 24] = res;
}

// K4b: delta = softplus(dt @ dt_proj^T + b), coalesced over d
__global__ void k_delta(const float* __restrict__ dt, const float* __restrict__ dtw,
                        const float* __restrict__ dtb, float* __restrict__ delta){
  __shared__ float dts[16][8];
  int r0 = blockIdx.x*16; int tid = threadIdx.x;
  if(tid < 128) ((float*)dts)[tid] = dt[r0*8 + tid];
  __syncthreads();
  int d = tid;
  float4 w0 = *(const float4*)&dtw[d*8];
  float4 w1 = *(const float4*)&dtw[d*8+4];
  float bb = dtb[d];
  #pragma unroll 4
  for(int r=0;r<16;r++){
    float acc = bb + dts[r][0]*w0.x + dts[r][1]*w0.y + dts[r][2]*w0.z + dts[r][3]*w0.w
                   + dts[r][4]*w1.x + dts[r][5]*w1.y + dts[r][6]*w1.z + dts[r][7]*w1.w;
    delta[(r0+r)*DI + d] = (acc > 20.f) ? acc : log1pf(__expf(acc));
  }
}

// K5: scan pass A — lanes=d coalesced; 4 states/thread; chunk aggregates (P,S)
__global__ void k_scanA(const float* __restrict__ delta, const float* __restrict__ xc,
                        const float* __restrict__ Bc, const float* __restrict__ A_log,
                        float* __restrict__ aggA, float* __restrict__ aggB){
  int b = blockIdx.x;                       // 1536 = 3*128*4
  int ng = b & 3, ch = (b>>2)&127, s = b>>9;
  int d = threadIdx.x;
  int n0 = ng*4;
  float Aa[4], P[4] = {1.f,1.f,1.f,1.f}, S[4] = {0.f,0.f,0.f,0.f};
  #pragma unroll
  for(int j=0;j<4;j++) Aa[j] = -__expf(A_log[d*NST + n0 + j]);
  int base = s*L + ch*CT;
  for(int st=0; st<CT; st++){
    int row = base + st;
    float dl = delta[row*DI + d];
    float u  = xc[row*DI + d];
    float4 bv = *(const float4*)&Bc[row*NST + n0];
    float dlu = dl*u;
    float a;
    a = __expf(dl*Aa[0]); S[0] = a*S[0] + dlu*bv.x; P[0] *= a;
    a = __expf(dl*Aa[1]); S[1] = a*S[1] + dlu*bv.y; P[1] *= a;
    a = __expf(dl*Aa[2]); S[2] = a*S[2] + dlu*bv.z; P[2] *= a;
    a = __expf(dl*Aa[3]); S[3] = a*S[3] + dlu*bv.w; P[3] *= a;
  }
  int idx0 = ch*R3 + s*256 + d;
  #pragma unroll
  for(int j=0;j<4;j++){
    int idx = idx0 + (n0+j)*768;
    aggA[idx] = P[j]; aggB[idx] = S[j];
  }
}

// K6: prefix over 128 chunk aggregates
__global__ void k_scanB(const float* __restrict__ aggA, const float* __restrict__ aggB,
                        float* __restrict__ hIn){
  int j = blockIdx.x*256 + threadIdx.x;  // < 12288
  float h = 0.f;
  for(int c=0;c<NCH;c++){
    hIn[c*R3 + j] = h;
    h = aggA[c*R3 + j]*h + aggB[c*R3 + j];
  }
}

// K7: scan pass C — lanes=d, all 16 states per thread, gate + store yz
__global__ void k_scanC(const float* __restrict__ delta, const float* __restrict__ xc,
                        const float* __restrict__ Bc, const float* __restrict__ Cc,
                        const float* __restrict__ A_log, const float* __restrict__ Dp,
                        const float* __restrict__ Z, const float* __restrict__ hIn,
                        float* __restrict__ yz){
  int b = blockIdx.x;                 // 384 = 3*128
  int ch = b & 127, s = b >> 7;
  int d = threadIdx.x;
  float Aa[16], h[16];
  #pragma unroll
  for(int n=0;n<16;n++) Aa[n] = -__expf(A_log[d*NST + n]);
  #pragma unroll
  for(int n=0;n<16;n++) h[n] = hIn[ch*R3 + n*768 + s*256 + d];
  float Dv = Dp[d];
  int base = s*L + ch*CT;
  for(int st=0; st<CT; st++){
    int row = base + st;
    float dl = delta[row*DI + d];
    float u  = xc[row*DI + d];
    float dlu = dl*u;
    const float4* Bp = (const float4*)&Bc[row*NST];
    const float4* Cp = (const float4*)&Cc[row*NST];
    float y = u*Dv;
    #pragma unroll
    for(int q=0;q<4;q++){
      float4 bv = Bp[q], cv = Cp[q];
      float a;
      a = __expf(dl*Aa[4*q+0]); h[4*q+0] = a*h[4*q+0] + dlu*bv.x; y += h[4*q+0]*cv.x;
      a = __expf(dl*Aa[4*q+1]); h[4*q+1] = a*h[4*q+1] + dlu*bv.y; y += h[4*q+1]*cv.y;
      a = __expf(dl*Aa[4*q+2]); h[4*q+2] = a*h[4*q+2] + dlu*bv.z; y += h[4*q+2]*cv.z;
      a = __expf(dl*Aa[4*q+3]); h[4*q+3] = a*h[4*q+3] + dlu*bv.w; y += h[4*q+3]*cv.w;
    }
    int l = ch*CT + st;
    int p = permf(s, l);
    float zv = Z[p*512 + 256 + d];
    yz[(s*L + l)*DI + d] = y * siluf(zv);
  }
}

// K8: out1 partials: pp[kc] = yz_slice @ M_slice  (tile 64x128, split-K=6)
__global__ void k_proj(const float* __restrict__ yz, const float* __restrict__ Mw,
                       float* __restrict__ pp){
  __shared__ float As[64][129];
  __shared__ float Bs[128][129];
  int p0 = blockIdx.x*64; int kc = blockIdx.y;  // 0..5
  int s = kc >> 1, d0 = (kc & 1)*128;
  int tid = threadIdx.x;
  for(int q=0;q<8;q++){
    int f = q*1024 + tid*4; int r = f>>7, k = f&127;
    float4 a = *(const float4*)&yz[(s*L + p0 + r)*DI + d0 + k];
    As[r][k]=a.x; As[r][k+1]=a.y; As[r][k+2]=a.z; As[r][k+3]=a.w;
  }
  for(int q=0;q<16;q++){
    int f = q*1024 + tid*4; int k = f>>7, o = f&127;
    float4 b = *(const float4*)&Mw[(s*256 + d0 + k)*128 + o];
    Bs[o][k]=b.x; Bs[o+1][k]=b.y; Bs[o+2][k]=b.z; Bs[o+3][k]=b.w;
  }
  __syncthreads();
  int og = tid & 15, r4 = tid >> 4;
  float acc[4][8] = {};
  for(int k=0;k<128;k++){
    float a[4];
    #pragma unroll
    for(int i=0;i<4;i++) a[i] = As[r4*4+i][k];
    #pragma unroll
    for(int j=0;j<8;j++){
      float bb = Bs[og+16*j][k];
      #pragma unroll
      for(int i=0;i<4;i++) acc[i][j] += a[i]*bb;
    }
  }
  float* dst = pp + kc*524288;
  #pragma unroll
  for(int i=0;i<4;i++)
    #pragma unroll
    for(int j=0;j<8;j++)
      dst[(p0+r4*4+i)*C + og + 16*j] = acc[i][j];
}

// K8b: ores = sum(pp) + x^T + pb
__global__ void k_pred(const float* __restrict__ pp, const float* __restrict__ x,
                       const float* __restrict__ pb, float* __restrict__ ores){
  __shared__ float Xs[16][129];
  int p0 = blockIdx.x*16; int tid = threadIdx.x;
  for(int q=0;q<8;q++){
    int f = q*256 + tid; int pl = f&15, o = f>>4;
    Xs[pl][o] = x[o*L + p0 + pl];
  }
  __syncthreads();
  for(int q=0;q<8;q++){
    int f = q*256 + tid; int o = f&127, pl = f>>7;
    int idx = (p0+pl)*C + o;
    float v = pp[idx] + pp[524288+idx] + pp[1048576+idx]
            + pp[1572864+idx] + pp[2097152+idx] + pp[2621440+idx];
    ores[idx] = v + Xs[pl][o] + pb[o];
  }
}

// K9a: T = LN(ores)
__global__ void k_ln2(const float* __restrict__ ores, const float* __restrict__ lw,
                      const float* __restrict__ lb, float* __restrict__ T){
  __shared__ float R[16][129];
  __shared__ float Ts[16][129];
  int p0 = blockIdx.x*16; int tid = threadIdx.x;
  for(int q=0;q<8;q++){
    int f = q*256 + tid; int r = f>>7, c = f&127;
    R[r][c] = ores[(p0+r)*C + c];
  }
  __syncthreads();
  int r = tid >> 4, sub = tid & 15;
  float s=0.f, sq=0.f;
  #pragma unroll
  for(int q=0;q<8;q++){ float v = R[r][sub*8+q]; s += v; sq += v*v; }
  s  += __shfl_xor(s,1);  s  += __shfl_xor(s,2);  s  += __shfl_xor(s,4);  s  += __shfl_xor(s,8);
  sq += __shfl_xor(sq,1); sq += __shfl_xor(sq,2); sq += __shfl_xor(sq,4); sq += __shfl_xor(sq,8);
  float mean = s*(1.f/C); float var = sq*(1.f/C) - mean*mean;
  float rr = rsqrtf(var + 1e-6f);
  #pragma unroll
  for(int q=0;q<8;q++){
    int c = sub*8+q; float v = R[r][c];
    Ts[r][c] = lw[c]*((v-mean)*rr) + lb[c];
  }
  __syncthreads();
  for(int q=0;q<8;q++){
    int f = q*256 + tid; int r2 = f>>7, c = f&127;
    T[(p0+r2)*C + c] = Ts[r2][c];
  }
}

// K9b: H = gelu(T @ w1^T + b1)
__global__ void k_fc1(const float* __restrict__ T, const float* __restrict__ w1,
                      const float* __restrict__ b1, float* __restrict__ H){
  __shared__ float As[64][129];
  __shared__ float Bs[64][129];
  int p0 = blockIdx.x*64, j0 = blockIdx.y*64;
  int tid = threadIdx.x;
  for(int q=0;q<8;q++){
    int f = q*1024 + tid*4; int r = f>>7, k = f&127;
    float4 a = *(const float4*)&T[(p0+r)*C + k];
    As[r][k]=a.x; As[r][k+1]=a.y; As[r][k+2]=a.z; As[r][k+3]=a.w;
    float4 b = *(const float4*)&w1[(j0+r)*C + k];
    Bs[r][k]=b.x; Bs[r][k+1]=b.y; Bs[r][k+2]=b.z; Bs[r][k+3]=b.w;
  }
  __syncthreads();
  int og = tid & 15, r4 = tid >> 4;
  float acc[4][4] = {};
  for(int k=0;k<128;k++){
    float a[4], b[4];
    #pragma unroll
    for(int i=0;i<4;i++) a[i] = As[r4*4+i][k];
    #pragma unroll
    for(int j=0;j<4;j++) b[j] = Bs[og+16*j][k];
    #pragma unroll
    for(int i=0;i<4;i++)
      #pragma unroll
      for(int j=0;j<4;j++) acc[i][j] += a[i]*b[j];
  }
  #pragma unroll
  for(int i=0;i<4;i++)
    #pragma unroll
    for(int j=0;j<4;j++){
      int jj = j0 + og + 16*j;
      H[(p0+r4*4+i)*512 + jj] = geluf(acc[i][j] + b1[jj]);
    }
}

// K9c: fc2 partials (tile 64x128, split-K=4)
__global__ void k_fc2(const float* __restrict__ H, const float* __restrict__ w2,
                      float* __restrict__ fp){
  __shared__ float As[64][129];
  __shared__ float Bs[128][129];
  int p0 = blockIdx.x*64; int kc = blockIdx.y; int k0 = kc*128;
  int tid = threadIdx.x;
  for(int q=0;q<8;q++){
    int f = q*1024 + tid*4; int r = f>>7, k = f&127;
    float4 a = *(const float4*)&H[(p0+r)*512 + k0 + k];
    As[r][k]=a.x; As[r][k+1]=a.y; As[r][k+2]=a.z; As[r][k+3]=a.w;
  }
  for(int q=0;q<16;q++){
    int f = q*1024 + tid*4; int o = f>>7, k = f&127;
    float4 b = *(const float4*)&w2[o*512 + k0 + k];
    Bs[o][k]=b.x; Bs[o][k+1]=b.y; Bs[o][k+2]=b.z; Bs[o][k+3]=b.w;
  }
  __syncthreads();
  int og = tid & 15, r4 = tid >> 4;
  float acc[4][8] = {};
  for(int k=0;k<128;k++){
    float a[4];
    #pragma unroll
    for(int i=0;i<4;i++) a[i] = As[r4*4+i][k];
    #pragma unroll
    for(int j=0;j<8;j++){
      float bb = Bs[og+16*j][k];
      #pragma unroll
      for(int i=0;i<4;i++) acc[i][j] += a[i]*bb;
    }
  }
  float* dst = fp + kc*524288;
  #pragma unroll
  for(int i=0;i<4;i++)
    #pragma unroll
    for(int j=0;j<8;j++)
      dst[(p0+r4*4+i)*C + og + 16*j] = acc[i][j];
}

// K9d: out = sum(fp) + b2 + ores, transposed store
__global__ void k_fred(const float* __restrict__ fp, const float* __restrict__ b2,
                       const float* __restrict__ ores, float* __restrict__ out){
  __shared__ float S[128][17];
  int p0 = blockIdx.x*16; int tid = threadIdx.x;
  for(int q=0;q<8;q++){
    int f = q*256 + tid; int o = f&127, pl = f>>7;
    int idx = (p0+pl)*C + o;
    float v = fp[idx] + fp[524288+idx] + fp[1048576+idx] + fp[1572864+idx];
    S[o][pl] = v + b2[o] + ores[idx];
  }
  __syncthreads();
  for(int q=0;q<8;q++){
    int f = q*256 + tid; int pl = f&15, o = f>>4;
    out[o*L + p0 + pl] = S[o][pl];
  }
}

extern "C" void kernel_launch(void* const* d_in, const int* in_sizes, int n_in,
                              void* d_out, int out_size, void* d_ws, size_t ws_size,
                              hipStream_t stream) {
  const float* x     = (const float*)d_in[0];
  const float* ln_w  = (const float*)d_in[1];
  const float* ln_b  = (const float*)d_in[2];
  const float* mw    = (const float*)d_in[3];
  const float* mb    = (const float*)d_in[4];
  const float* ipw   = (const float*)d_in[5];
  const float* cw    = (const float*)d_in[6];
  const float* cb    = (const float*)d_in[7];
  const float* xpw   = (const float*)d_in[8];
  const float* dtw   = (const float*)d_in[9];
  const float* dtb   = (const float*)d_in[10];
  const float* A_log = (const float*)d_in[11];
  const float* Dp    = (const float*)d_in[12];
  const float* opw   = (const float*)d_in[13];
  const float* pw    = (const float*)d_in[14];
  const float* pb    = (const float*)d_in[15];
  const float* w1    = (const float*)d_in[16];
  const float* b1    = (const float*)d_in[17];
  const float* w2    = (const float*)d_in[18];
  const float* b2    = (const float*)d_in[19];
  float* out = (float*)d_out;

  float* ws = (float*)d_ws;
  float* Z     = ws;                       // 2097152
  float* xc    = Z     + 2097152;          // 3145728
  float* delta = xc    + 3145728;          // 3145728
  float* dt    = delta + 3145728;          // 98304
  float* Bc    = dt    + 98304;            // 196608
  float* Cc    = Bc    + 196608;           // 196608
  float* aggA  = Cc    + 196608;           // 1572864
  float* aggB  = aggA  + 1572864;          // 1572864
  float* hIn   = aggB  + 1572864;          // 1572864
  float* Mw    = hIn   + 1572864;          // 98304
  float* ores  = Mw    + 98304;            // 524288
  // aliases (regions dead after scanC reused)
  float* yz = aggA;    // 3145728 (aggA+aggB), written by scanC after scanB consumed
  float* pp = delta;   // 6*524288, written by k_proj after scanC
  float* T  = hIn;     // 524288, after scanC
  float* H  = Z;       // 2097152, after scanC
  float* fp = xc;      // 4*524288, after scanC

  k_M     <<<384, 256, 0, stream>>>(opw, pw, Mw);
  k_lngemm<<<dim3(64,8), 256, 0, stream>>>(x, ln_w, ln_b, mw, mb, ipw, Z);
  k_conv  <<<NS*L, 256, 0, stream>>>(Z, cw, cb, xc);
  k_xdbl1 <<<3072, 256, 0, stream>>>(xc, xpw, dt, Bc, Cc);
  k_delta <<<768, 256, 0, stream>>>(dt, dtw, dtb, delta);
  k_scanA <<<1536, 256, 0, stream>>>(delta, xc, Bc, A_log, aggA, aggB);
  k_scanB <<<48, 256, 0, stream>>>(aggA, aggB, hIn);
  k_scanC <<<384, 256, 0, stream>>>(delta, xc, Bc, Cc, A_log, Dp, Z, hIn, yz);
  k_proj  <<<dim3(64,6), 256, 0, stream>>>(yz, Mw, pp);
  k_pred  <<<256, 256, 0, stream>>>(pp, x, pb, ores);
  k_ln2   <<<256, 256, 0, stream>>>(ores, ln_w, ln_b, T);
  k_fc1   <<<dim3(64,8), 256, 0, stream>>>(T, w1, b1, H);
  k_fc2   <<<dim3(64,4), 256, 0, stream>>>(H, w2, fp);
  k_fred  <<<256, 256, 0, stream>>>(fp, b2, ores, out);
}